// Round 17
// baseline (95.219 us; speedup 1.0000x reference)
//
#include <hip/hip_runtime.h>
#include <hip/hip_bf16.h>

typedef __attribute__((ext_vector_type(8))) short bf16x8;
typedef __attribute__((ext_vector_type(4))) float f32x4;
typedef __attribute__((ext_vector_type(4))) unsigned short us4;

__device__ __forceinline__ unsigned short f2bf(float f) {
    union { float f; unsigned u; } c; c.f = f;
    unsigned u = c.u;
    u += 0x7fffu + ((u >> 16) & 1u);   // RNE (no NaNs in this problem)
    return (unsigned short)(u >> 16);
}
__device__ __forceinline__ float bf2f(unsigned short h) {
    union { unsigned u; float f; } c; c.u = ((unsigned)h) << 16;
    return c.f;
}
__device__ __forceinline__ unsigned cvt_pk_bf16(float lo, float hi) {
    unsigned r;
    asm volatile("v_cvt_pk_bf16_f32 %0, %1, %2" : "=v"(r) : "v"(lo), "v"(hi));
    return r;
}
__device__ __forceinline__ void gload_lds16(const void* g, void* l) {
    __builtin_amdgcn_global_load_lds(
        (const __attribute__((address_space(1))) unsigned int*)g,
        (__attribute__((address_space(3))) unsigned int*)l, 16, 0, 0);
}

// scale folded into q at GEMM epilogue: C^-0.5 * log2(e)  (exp2 domain)
#define QSCALE 0.04508422f

// ---------------- Kernel 1: W -> WbT (bf16, transposed, [384][1024]) -------
__global__ __launch_bounds__(256) void wconv_kernel(
        const float* __restrict__ Wk, const float* __restrict__ Wq,
        const float* __restrict__ Wv, unsigned short* __restrict__ WbT) {
    int idx = blockIdx.x * 256 + threadIdx.x;     // 384*1024 total
    int n = idx >> 10, kk = idx & 1023;
    const float* W = (n < 128) ? Wk : (n < 256) ? Wq : Wv;
    int col = n & 127;
    WbT[idx] = f2bf(W[kk * 128 + col]);
}

// ---------------- Kernel 2: fused QKV projection GEMM (r13, unchanged) -----
__global__ __launch_bounds__(512) void qkv_gemm_kernel(
        const float* __restrict__ x, const unsigned short* __restrict__ WbT,
        unsigned short* __restrict__ kw, unsigned short* __restrict__ qw,
        unsigned short* __restrict__ vTw) {
    __shared__ __align__(16) unsigned short Bl[2][192 * 64];  // 2x24KB, linear
    __shared__ __align__(16) unsigned short Al[2][64 * 72];   // 2x9KB, padded
    const int tid = threadIdx.x;
    const int m0 = (blockIdx.x >> 1) * 64;
    const int nb = blockIdx.x & 1;                // N half: cols nb*192..+192
    const int w = tid >> 6, l = tid & 63;
    const int l15 = l & 15, lh = l >> 4;
    const int wm = w >> 2, wn = w & 3;            // 2M x 4N waves

    f32x4 acc[2][3] = {};

    const int srcsw = ((((l & 7) * 16) ^ ((l >> 3) << 4)) >> 1); // elems
    const unsigned short* gB[3];
    #pragma unroll
    for (int it = 0; it < 3; ++it)
        gB[it] = WbT + (size_t)(nb * 192 + it * 64 + w * 8 + (l >> 3)) * 1024 + srcsw;

    const float* xr = &x[(size_t)(m0 + (tid >> 3)) * 1024 + (tid & 7) * 8];
    const int aoff = (tid >> 3) * 72 + (tid & 7) * 8;

    float4 aE0, aE1, aO0, aO1;                    // 2-deep named A sets

    #define STAGE_B(buf, t_) do { \
        _Pragma("unroll") \
        for (int it = 0; it < 3; ++it) \
            gload_lds16(gB[it] + (t_) * 64, &Bl[buf][(it * 64 + w * 8) * 64]); \
    } while (0)
    #define ISSUE_A(d0, d1, t_) do { \
        d0 = *(const float4*)(xr + (t_) * 64); \
        d1 = *(const float4*)(xr + (t_) * 64 + 4); } while (0)
    #define WRITE_A(buf, s0, s1) do { \
        uint4 pk_; \
        pk_.x = cvt_pk_bf16(s0.x, s0.y); pk_.y = cvt_pk_bf16(s0.z, s0.w); \
        pk_.z = cvt_pk_bf16(s1.x, s1.y); pk_.w = cvt_pk_bf16(s1.z, s1.w); \
        *(uint4*)&Al[buf][aoff] = pk_; } while (0)
    #define MFMA_ON(buf) do { \
        for (int kc = 0; kc < 2; ++kc) { \
            bf16x8 a_[2], bb_[3]; \
            for (int mi = 0; mi < 2; ++mi) \
                a_[mi] = *(const bf16x8*)&Al[buf][(wm * 32 + mi * 16 + l15) * 72 + kc * 32 + lh * 8]; \
            for (int ni = 0; ni < 3; ++ni) { \
                int n_ = wn * 48 + ni * 16 + l15; \
                bb_[ni] = *(const bf16x8*)((const char*)Bl[buf] + n_ * 128 + \
                        ((kc * 64 + lh * 16) ^ ((n_ & 7) << 4))); \
            } \
            for (int mi = 0; mi < 2; ++mi) \
                for (int ni = 0; ni < 3; ++ni) \
                    acc[mi][ni] = __builtin_amdgcn_mfma_f32_16x16x32_bf16( \
                            a_[mi], bb_[ni], acc[mi][ni], 0, 0, 0); \
        } } while (0)
    #define BAR(n_) do { \
        asm volatile("s_waitcnt vmcnt(" #n_ ") lgkmcnt(0)" ::: "memory"); \
        __builtin_amdgcn_sched_barrier(0); \
        __builtin_amdgcn_s_barrier(); } while (0)

    STAGE_B(0, 0);
    ISSUE_A(aE0, aE1, 0);
    ISSUE_A(aO0, aO1, 1);
    WRITE_A(0, aE0, aE1);
    BAR(2);

    #pragma unroll 1
    for (int tt = 0; tt < 8; ++tt) {
        const int t0 = tt * 2;
        STAGE_B(1, t0 + 1);
        if (t0 + 2 < 16) ISSUE_A(aE0, aE1, t0 + 2);
        MFMA_ON(0);
        WRITE_A(1, aO0, aO1);
        if (t0 + 2 < 16) BAR(2); else BAR(0);
        if (t0 + 2 < 16) {
            STAGE_B(0, t0 + 2);
            if (t0 + 3 < 16) ISSUE_A(aO0, aO1, t0 + 3);
            MFMA_ON(1);
            WRITE_A(0, aE0, aE1);
            if (t0 + 3 < 16) BAR(2); else BAR(0);
        } else {
            MFMA_ON(1);
        }
    }
    #undef STAGE_B
    #undef ISSUE_A
    #undef WRITE_A
    #undef MFMA_ON
    #undef BAR

    for (int mi = 0; mi < 2; ++mi)
        for (int ni = 0; ni < 3; ++ni) {
            int col = nb * 192 + wn * 48 + ni * 16 + l15;
            int sect = col >> 7, cc = col & 127;
            if (sect < 2) {
                unsigned short* dst = (sect == 0) ? kw : qw;
                float fs = (sect == 0) ? 1.0f : QSCALE;
                for (int i = 0; i < 4; ++i) {
                    int row = m0 + wm * 32 + mi * 16 + lh * 4 + i;
                    dst[(size_t)row * 128 + cc] = f2bf(acc[mi][ni][i] * fs);
                }
            } else {
                int trow0 = m0 + wm * 32 + mi * 16 + lh * 4;
                int b = trow0 >> 12, t0_ = trow0 & 4095;
                union { unsigned short u[4]; us4 v; } pk;
                for (int i = 0; i < 4; ++i) pk.u[i] = f2bf(acc[mi][ni][i]);
                *(us4*)&vTw[((size_t)(b * 128 + cc)) * 4096 + t0_] = pk.v;
            }
        }
}

// ---------------- Kernel 3: split-KV flash attention (STATIC softmax) ------
// QBLK=128 (8 waves x 16 q-rows), KVBLK=64, chunk<=4 kv-tiles (1088 blocks),
// swapped QK^T, m==0 softmax. TWO-DEEP named-set K/V prefetch: set-p is
// written to LDS at iteration kt (its loads issued at kt-2), then re-issued
// for kt+2. Cross-iteration use in a rolled loop -> compiler cannot sink the
// loads to their use point; 32 live staging VGPRs + o(32) + qa(16) forbid
// the 64-VGPR squeeze that cost r11-r16 ~10us (r9/r10 ran ~29us at ~100 VGPR).
__global__ __launch_bounds__(512) void attn_kernel(
        const unsigned short* __restrict__ kw, const unsigned short* __restrict__ qw,
        const unsigned short* __restrict__ vTw,
        unsigned short* __restrict__ pO, float* __restrict__ pL,
        int nCPB, int G, int TPC) {
    __shared__ __align__(16) unsigned short Kl[64 * 128];   // swizzled, 16KB
    __shared__ __align__(16) unsigned short Vl[128 * 64];   // swizzled, 16KB
    __shared__ __align__(16) unsigned short Pl[8][1024];    // swizzled, 16KB

    const int tid = threadIdx.x;
    const int wgid = blockIdx.x;                  // 0 .. 4*nCPB-1
    const int xcd = wgid & 7, slot = wgid >> 3;
    const int b = xcd >> 1, half = xcd & 1;
    const int cid = (nCPB - 1) - (slot * 2 + half);     // longest first
    const int halfG = G >> 1;
    int a = 0;
    while (halfG * (a + 1) * (a + 2) <= cid) ++a;
    int rem = cid - halfG * a * (a + 1);
    const int g = G * a + rem / (a + 1);
    const int c = rem % (a + 1);
    const int kt0 = c * TPC;
    const int kt1 = min(kt0 + TPC, 2 * g + 2);

    const int w = tid >> 6, l = tid & 63;
    const int l15 = l & 15, lh = l >> 4;
    const int qrow0 = g * 128 + w * 16;           // wave's first q row (in-batch)

    bf16x8 qa[4];
    {
        size_t grow = (size_t)b * 4096 + qrow0 + l15;
        for (int cc = 0; cc < 4; ++cc)
            qa[cc] = *(const bf16x8*)&qw[grow * 128 + cc * 32 + lh * 8];
    }
    bf16x8 ones;
    for (int u = 0; u < 8; ++u) ones[u] = (short)0x3F80;    // 1.0 bf16

    f32x4 o[8] = {};
    f32x4 lsa = {0.f, 0.f, 0.f, 0.f};             // row-sum acc (MFMA ones)

    const int kr_ = tid >> 3;                     // K: 1 row, 32B/thread
    const int vd_ = tid >> 2;                     // V: 1 row, 32B/thread
    // two named staging sets (rule #20: no runtime-indexed arrays)
    bf16x8 kA0, kA1, vA0, vA1, kB0, kB1, vB0, vB1;

    const unsigned short* kbase = &kw[((size_t)(b * 4096 + kr_)) * 128 + (tid & 7) * 16];
    const unsigned short* vbase = &vTw[((size_t)(b * 128 + vd_)) * 4096 + (tid & 3) * 16];

    #define ISSUE_SET(K0, K1, V0, V1, kt_) do { \
        const unsigned short* ks_ = kbase + (size_t)(kt_) * 64 * 128; \
        K0 = *(const bf16x8*)ks_; \
        K1 = *(const bf16x8*)(ks_ + 8); \
        const unsigned short* vs_ = vbase + (kt_) * 64; \
        V0 = *(const bf16x8*)vs_; \
        V1 = *(const bf16x8*)(vs_ + 8); } while (0)
    #define WRITE_SET(K0, K1, V0, V1) do { \
        *(bf16x8*)((char*)Kl + kr_ * 256 + (((tid & 7) * 32) ^ ((kr_ & 7) << 4))) = K0; \
        *(bf16x8*)((char*)Kl + kr_ * 256 + (((tid & 7) * 32 + 16) ^ ((kr_ & 7) << 4))) = K1; \
        *(bf16x8*)((char*)Vl + vd_ * 128 + (((tid & 3) * 32) ^ ((vd_ & 7) << 4))) = V0; \
        *(bf16x8*)((char*)Vl + vd_ * 128 + (((tid & 3) * 32 + 16) ^ ((vd_ & 7) << 4))) = V1; } while (0)

    char* Plw = (char*)&Pl[w][0];

    ISSUE_SET(kA0, kA1, vA0, vA1, kt0);
    if (kt0 + 1 < kt1) ISSUE_SET(kB0, kB1, vB0, vB1, kt0 + 1);
    bool p = false;                               // uniform parity flag

    for (int kt = kt0; kt < kt1; ++kt) {
        __syncthreads();                          // prev-tile readers done
        if (!p) WRITE_SET(kA0, kA1, vA0, vA1);
        else    WRITE_SET(kB0, kB1, vB0, vB1);
        __syncthreads();                          // tile visible
        if (kt + 2 < kt1) {                       // re-issue consumed set, 2 ahead
            if (!p) ISSUE_SET(kA0, kA1, vA0, vA1, kt + 2);
            else    ISSUE_SET(kB0, kB1, vB0, vB1, kt + 2);
            __builtin_amdgcn_sched_barrier(0);
        }
        p = !p;

        const int kv0 = kt * 64;
        if (kv0 > qrow0 + 15) continue;           // fully masked for this wave

        // S^T = K Q^T : s[ni][i] = S[q=qrow0+l15][kv=kv0+ni*16+lh*4+i]
        f32x4 s[4];
        __builtin_amdgcn_s_setprio(1);
        for (int ni = 0; ni < 4; ++ni) {
            s[ni] = (f32x4){0.f, 0.f, 0.f, 0.f};
            int kr = ni * 16 + l15;
            int sw = (kr & 7) << 4;
            for (int cc = 0; cc < 4; ++cc) {
                bf16x8 bk = *(bf16x8*)((char*)Kl + kr * 256 + ((lh * 16 + cc * 64) ^ sw));
                s[ni] = __builtin_amdgcn_mfma_f32_16x16x32_bf16(bk, qa[cc], s[ni], 0, 0, 0);
            }
        }
        __builtin_amdgcn_s_setprio(0);

        if (kv0 + 63 > qrow0) {                   // causal mask (near-diag only)
            int qg = qrow0 + l15;
            for (int ni = 0; ni < 4; ++ni)
                for (int i = 0; i < 4; ++i)
                    if (kv0 + ni * 16 + lh * 4 + i > qg) s[ni][i] = -INFINITY;
        }
        // P = exp2(s) -> pack 4 consecutive kv as b64, row q=l15, swizzled
        for (int ni = 0; ni < 4; ++ni) {
            float p0 = exp2f(s[ni][0]), p1 = exp2f(s[ni][1]);
            float p2 = exp2f(s[ni][2]), p3 = exp2f(s[ni][3]);
            uint2 pk;
            pk.x = cvt_pk_bf16(p0, p1);
            pk.y = cvt_pk_bf16(p2, p3);
            *(uint2*)(Plw + l15 * 128 + ((ni * 32 + lh * 8) ^ ((l15 & 7) << 4))) = pk;
        }
        bf16x8 pa[2];
        for (int kc = 0; kc < 2; ++kc)
            pa[kc] = *(bf16x8*)(Plw + l15 * 128 +
                    ((kc * 64 + lh * 16) ^ ((l15 & 7) << 4)));
        __builtin_amdgcn_s_setprio(1);
        // row-sums via MFMA against ones
        lsa = __builtin_amdgcn_mfma_f32_16x16x32_bf16(pa[1], ones,
              __builtin_amdgcn_mfma_f32_16x16x32_bf16(pa[0], ones, lsa, 0, 0, 0), 0, 0, 0);
        for (int nd = 0; nd < 8; ++nd) {
            int dr = nd * 16 + l15;
            int sw = (dr & 7) << 4;
            for (int kc = 0; kc < 2; ++kc) {
                bf16x8 bv = *(bf16x8*)((char*)Vl + dr * 128 + ((lh * 16 + kc * 64) ^ sw));
                o[nd] = __builtin_amdgcn_mfma_f32_16x16x32_bf16(pa[kc], bv, o[nd], 0, 0, 0);
            }
        }
        __builtin_amdgcn_s_setprio(0);
    }
    #undef ISSUE_SET
    #undef WRITE_SET

    // epilogue: unnormalized partial O (bf16) + l (f32), compact slot
    const int slot_ = b * nCPB + cid;
    unsigned short* po = pO + (size_t)slot_ * 16384;
    for (int nd = 0; nd < 8; ++nd)
        for (int i = 0; i < 4; ++i)
            po[(w * 16 + lh * 4 + i) * 128 + nd * 16 + l15] = f2bf(o[nd][i]);
    if (l15 == 0) {
        float* pl = pL + (size_t)slot_ * 128;
        for (int i = 0; i < 4; ++i)
            pl[w * 16 + lh * 4 + i] = lsa[i];
    }
}

// ---------------- Kernel 4: combine partials (plain sums, no weights) ------
__global__ __launch_bounds__(256) void combine_kernel(
        const unsigned short* __restrict__ pO, const float* __restrict__ pL,
        float* __restrict__ out, int nCPB, int G) {
    int idx = blockIdx.x * 256 + threadIdx.x;     // B*T*16 = 262144 threads
    int row = idx >> 4, d8 = (idx & 15) * 8;
    int b = row >> 12, t = row & 4095;
    int g = t >> 7, rowin = t & 127;
    int a = g / G;
    int nch = a + 1;
    int base = b * nCPB + (G >> 1) * a * (a + 1) + (g - G * a) * (a + 1);

    float den = 0.f;
    float num[8] = {0.f, 0.f, 0.f, 0.f, 0.f, 0.f, 0.f, 0.f};
    for (int cc = 0; cc < nch; ++cc) {
        den += pL[(size_t)(base + cc) * 128 + rowin];
        bf16x8 ov = *(const bf16x8*)&pO[(size_t)(base + cc) * 16384 + rowin * 128 + d8];
        for (int u = 0; u < 8; ++u)
            num[u] += bf2f((unsigned short)ov[u]);
    }
    float inv = 1.f / den;
    for (int u = 0; u < 8; ++u)
        out[(size_t)row * 128 + d8 + u] = num[u] * inv;
}

// ---------------------------------------------------------------------------
extern "C" void kernel_launch(void* const* d_in, const int* in_sizes, int n_in,
                              void* d_out, int out_size, void* d_ws, size_t ws_size,
                              hipStream_t stream) {
    const float* x  = (const float*)d_in[0];
    const float* Wk = (const float*)d_in[1];
    const float* Wq = (const float*)d_in[2];
    const float* Wv = (const float*)d_in[3];
    float* out = (float*)d_out;

    // ws: WbT 786432 | k/q/vT 3*4194304 | pO nslots*32768 | pL nslots*512
    char* ws = (char*)d_ws;
    unsigned short* WbT = (unsigned short*)(ws);
    unsigned short* kw  = (unsigned short*)(ws + 786432);
    unsigned short* qw  = (unsigned short*)(ws + 786432 + 4194304);
    unsigned short* vTw = (unsigned short*)(ws + 786432 + 2 * 4194304);
    size_t base = 786432 + 3 * (size_t)4194304;   // 13369344

    // chunk=4 kv-tiles (272 chunks/batch) if ws allows, else chunk=8 (144)
    int nCPB, G, TPC;
    size_t need4 = base + (size_t)1088 * 32768 + (size_t)1088 * 512;
    if (ws_size >= need4) { nCPB = 272; G = 2; TPC = 4; }
    else                  { nCPB = 144; G = 4; TPC = 8; }
    int nslots = 4 * nCPB;
    unsigned short* pO = (unsigned short*)(ws + base);
    float*          pL = (float*)(ws + base + (size_t)nslots * 32768);

    wconv_kernel<<<1536, 256, 0, stream>>>(Wk, Wq, Wv, WbT);
    qkv_gemm_kernel<<<512, 512, 0, stream>>>(x, WbT, kw, qw, vTw);
    attn_kernel<<<nslots, 512, 0, stream>>>(kw, qw, vTw, pO, pL, nCPB, G, TPC);
    combine_kernel<<<1024, 256, 0, stream>>>(pO, pL, out, nCPB, G);
}

// Round 18
// 77.842 us; speedup vs baseline: 1.2232x; 1.2232x over previous
//
#include <hip/hip_runtime.h>
#include <hip/hip_bf16.h>

typedef __attribute__((ext_vector_type(8))) short bf16x8;
typedef __attribute__((ext_vector_type(4))) float f32x4;
typedef __attribute__((ext_vector_type(4))) unsigned short us4;

__device__ __forceinline__ unsigned short f2bf(float f) {
    union { float f; unsigned u; } c; c.f = f;
    unsigned u = c.u;
    u += 0x7fffu + ((u >> 16) & 1u);   // RNE (no NaNs in this problem)
    return (unsigned short)(u >> 16);
}
__device__ __forceinline__ float bf2f(unsigned short h) {
    union { unsigned u; float f; } c; c.u = ((unsigned)h) << 16;
    return c.f;
}
__device__ __forceinline__ unsigned cvt_pk_bf16(float lo, float hi) {
    unsigned r;
    asm volatile("v_cvt_pk_bf16_f32 %0, %1, %2" : "=v"(r) : "v"(lo), "v"(hi));
    return r;
}

// scale folded into q at GEMM epilogue: C^-0.5 * log2(e)  (exp2 domain)
#define QSCALE 0.04508422f

// ---------------- Kernel 1: W -> WbT (bf16, transposed, [384][1024]) -------
__global__ __launch_bounds__(256) void wconv_kernel(
        const float* __restrict__ Wk, const float* __restrict__ Wq,
        const float* __restrict__ Wv, unsigned short* __restrict__ WbT) {
    int idx = blockIdx.x * 256 + threadIdx.x;     // 384*1024 total
    int n = idx >> 10, kk = idx & 1023;
    const float* W = (n < 128) ? Wk : (n < 256) ? Wq : Wv;
    int col = n & 127;
    WbT[idx] = f2bf(W[kk * 128 + col]);
}

// ---------------- Kernel 2: fused QKV projection GEMM ----------------------
// One pass over x. Tile: 64 rows x 384 cols, 512 threads (8 waves, each
// 64x48). K-step 64 (24 MFMA/wave/step), TWO-DEEP register prefetch with
// named A/B reg sets (static indexing), 2 K-steps per loop iteration.
__global__ __launch_bounds__(512) void qkv_gemm_kernel(
        const float* __restrict__ x, const unsigned short* __restrict__ WbT,
        unsigned short* __restrict__ kw, unsigned short* __restrict__ qw,
        unsigned short* __restrict__ vTw) {
    __shared__ __align__(16) unsigned short Al[64 * 72];    // +8 pad
    __shared__ __align__(16) unsigned short Bl[384 * 72];   // +8 pad
    const int tid = threadIdx.x;
    const int m0 = blockIdx.x * 64;
    const int w = tid >> 6, l = tid & 63;
    const int l15 = l & 15, lh = l >> 4;

    f32x4 acc[4][3] = {};

    const int ar = tid >> 3, ac = (tid & 7) * 8;   // A: 8 fp32 per thread

    // two named register staging sets (NO runtime indexing -> no scratch)
    float4 aA0, aA1, aB0, aB1;
    bf16x8 bA0, bA1, bA2, bA3, bA4, bA5;
    bf16x8 bB0, bB1, bB2, bB3, bB4, bB5;

    const float* xr = &x[(size_t)(m0 + ar) * 1024 + ac];
    const unsigned short* wr0 = &WbT[(size_t)((0 * 512 + tid) >> 3) * 1024 + ((0 * 512 + tid) & 7) * 8];
    const unsigned short* wr1 = &WbT[(size_t)((1 * 512 + tid) >> 3) * 1024 + ((1 * 512 + tid) & 7) * 8];
    const unsigned short* wr2 = &WbT[(size_t)((2 * 512 + tid) >> 3) * 1024 + ((2 * 512 + tid) & 7) * 8];
    const unsigned short* wr3 = &WbT[(size_t)((3 * 512 + tid) >> 3) * 1024 + ((3 * 512 + tid) & 7) * 8];
    const unsigned short* wr4 = &WbT[(size_t)((4 * 512 + tid) >> 3) * 1024 + ((4 * 512 + tid) & 7) * 8];
    const unsigned short* wr5 = &WbT[(size_t)((5 * 512 + tid) >> 3) * 1024 + ((5 * 512 + tid) & 7) * 8];

    #define ISSUE_A(k0) do { \
        aA0 = *(const float4*)(xr + (k0)); aA1 = *(const float4*)(xr + (k0) + 4); \
        bA0 = *(const bf16x8*)(wr0 + (k0)); bA1 = *(const bf16x8*)(wr1 + (k0)); \
        bA2 = *(const bf16x8*)(wr2 + (k0)); bA3 = *(const bf16x8*)(wr3 + (k0)); \
        bA4 = *(const bf16x8*)(wr4 + (k0)); bA5 = *(const bf16x8*)(wr5 + (k0)); } while (0)
    #define ISSUE_B(k0) do { \
        aB0 = *(const float4*)(xr + (k0)); aB1 = *(const float4*)(xr + (k0) + 4); \
        bB0 = *(const bf16x8*)(wr0 + (k0)); bB1 = *(const bf16x8*)(wr1 + (k0)); \
        bB2 = *(const bf16x8*)(wr2 + (k0)); bB3 = *(const bf16x8*)(wr3 + (k0)); \
        bB4 = *(const bf16x8*)(wr4 + (k0)); bB5 = *(const bf16x8*)(wr5 + (k0)); } while (0)
    // stage write: A-tile converted via cvt_pk, B-tile raw
    #define WRITE_SET(a0, a1, b0, b1, b2, b3, b4, b5) do { \
        us4 p; \
        p.x = (unsigned short)(cvt_pk_bf16(a0.x, a0.y) & 0xffff); \
        p.y = (unsigned short)(cvt_pk_bf16(a0.x, a0.y) >> 16); \
        p.z = (unsigned short)(cvt_pk_bf16(a0.z, a0.w) & 0xffff); \
        p.w = (unsigned short)(cvt_pk_bf16(a0.z, a0.w) >> 16); \
        *(us4*)&Al[ar * 72 + ac] = p; \
        p.x = (unsigned short)(cvt_pk_bf16(a1.x, a1.y) & 0xffff); \
        p.y = (unsigned short)(cvt_pk_bf16(a1.x, a1.y) >> 16); \
        p.z = (unsigned short)(cvt_pk_bf16(a1.z, a1.w) & 0xffff); \
        p.w = (unsigned short)(cvt_pk_bf16(a1.z, a1.w) >> 16); \
        *(us4*)&Al[ar * 72 + ac + 4] = p; \
        *(bf16x8*)&Bl[((0 * 512 + tid) >> 3) * 72 + ((0 * 512 + tid) & 7) * 8] = b0; \
        *(bf16x8*)&Bl[((1 * 512 + tid) >> 3) * 72 + ((1 * 512 + tid) & 7) * 8] = b1; \
        *(bf16x8*)&Bl[((2 * 512 + tid) >> 3) * 72 + ((2 * 512 + tid) & 7) * 8] = b2; \
        *(bf16x8*)&Bl[((3 * 512 + tid) >> 3) * 72 + ((3 * 512 + tid) & 7) * 8] = b3; \
        *(bf16x8*)&Bl[((4 * 512 + tid) >> 3) * 72 + ((4 * 512 + tid) & 7) * 8] = b4; \
        *(bf16x8*)&Bl[((5 * 512 + tid) >> 3) * 72 + ((5 * 512 + tid) & 7) * 8] = b5; } while (0)
    #define MFMA_TILE() do { \
        for (int kc = 0; kc < 2; ++kc) { \
            bf16x8 a[4], bb[3]; \
            for (int mi = 0; mi < 4; ++mi) \
                a[mi] = *(bf16x8*)&Al[(mi * 16 + l15) * 72 + kc * 32 + lh * 8]; \
            for (int ni = 0; ni < 3; ++ni) \
                bb[ni] = *(bf16x8*)&Bl[(w * 48 + ni * 16 + l15) * 72 + kc * 32 + lh * 8]; \
            for (int mi = 0; mi < 4; ++mi) \
                for (int ni = 0; ni < 3; ++ni) \
                    acc[mi][ni] = __builtin_amdgcn_mfma_f32_16x16x32_bf16( \
                            a[mi], bb[ni], acc[mi][ni], 0, 0, 0); \
        } } while (0)

    ISSUE_A(0);
    ISSUE_B(64);
    for (int t = 0; t < 16; t += 2) {
        WRITE_SET(aA0, aA1, bA0, bA1, bA2, bA3, bA4, bA5);
        __syncthreads();                        // tile t visible
        if (t + 2 < 16) ISSUE_A((t + 2) * 64);  // 2 steps of latency budget
        MFMA_TILE();
        __syncthreads();                        // readers done
        WRITE_SET(aB0, aB1, bB0, bB1, bB2, bB3, bB4, bB5);
        __syncthreads();                        // tile t+1 visible
        if (t + 3 < 16) ISSUE_B((t + 3) * 64);
        MFMA_TILE();
        __syncthreads();                        // readers done
    }

    for (int mi = 0; mi < 4; ++mi)
        for (int ni = 0; ni < 3; ++ni) {
            int col = w * 48 + ni * 16 + l15;  // 16-range never crosses 128
            int sect = col >> 7, cc = col & 127;
            if (sect < 2) {
                unsigned short* dst = (sect == 0) ? kw : qw;
                float fs = (sect == 0) ? 1.0f : QSCALE;  // fold attn scale into q
                for (int i = 0; i < 4; ++i) {
                    int row = m0 + mi * 16 + lh * 4 + i;
                    dst[(size_t)row * 128 + cc] = f2bf(acc[mi][ni][i] * fs);
                }
            } else {
                int trow0 = m0 + mi * 16 + lh * 4;
                int b = trow0 >> 12, t0 = trow0 & 4095;
                union { unsigned short u[4]; us4 v; } pk;
                for (int i = 0; i < 4; ++i) pk.u[i] = f2bf(acc[ni == ni ? mi : mi][ni][i]);
                *(us4*)&vTw[((size_t)(b * 128 + cc)) * 4096 + t0] = pk.v;
            }
        }
    #undef ISSUE_A
    #undef ISSUE_B
    #undef WRITE_SET
    #undef MFMA_TILE
}

// ---------------- Kernel 3: split-KV flash attention (STATIC softmax) ------
// QBLK=128 (8 waves), KVBLK=64, static softmax shift (m==0). SWAPPED QK^T:
// mfma(K,Q) puts S with q=lane&15, kv lane-local consecutive -> P packs via
// cvt_pk + 4 ds_write_b64 (no scattered transpose writes). XCD-pinned.
__global__ __launch_bounds__(512) void attn_kernel(
        const unsigned short* __restrict__ kw, const unsigned short* __restrict__ qw,
        const unsigned short* __restrict__ vTw,
        unsigned short* __restrict__ pO, float* __restrict__ pL,
        int nCPB, int G, int TPC) {
    __shared__ __align__(16) unsigned short Kl[64 * 128];   // swizzled, 16KB
    __shared__ __align__(16) unsigned short Vl[128 * 64];   // swizzled, 16KB
    __shared__ __align__(16) unsigned short Pl[8][1024];    // swizzled, 16KB

    const int tid = threadIdx.x;
    const int wgid = blockIdx.x;                  // 0 .. 4*nCPB-1
    const int xcd = wgid & 7, slot = wgid >> 3;
    const int b = xcd >> 1, half = xcd & 1;
    const int cid = (nCPB - 1) - (slot * 2 + half);     // longest first
    const int halfG = G >> 1;
    int a = 0;
    while (halfG * (a + 1) * (a + 2) <= cid) ++a;
    int rem = cid - halfG * a * (a + 1);
    const int g = G * a + rem / (a + 1);
    const int c = rem % (a + 1);
    const int kt0 = c * TPC;
    const int kt1 = min(kt0 + TPC, 2 * g + 2);

    const int w = tid >> 6, l = tid & 63;
    const int l15 = l & 15, lh = l >> 4;
    const int qrow0 = g * 128 + w * 16;           // wave's first q row (in-batch)

    bf16x8 qa[4];
    {
        size_t grow = (size_t)b * 4096 + qrow0 + l15;
        for (int cc = 0; cc < 4; ++cc)
            qa[cc] = *(const bf16x8*)&qw[grow * 128 + cc * 32 + lh * 8];
    }
    bf16x8 ones;
    for (int u = 0; u < 8; ++u) ones[u] = (short)0x3F80;    // 1.0 bf16

    f32x4 o[8] = {};
    f32x4 lsa = {0.f, 0.f, 0.f, 0.f};             // row-sum acc (MFMA ones)

    const int kr_ = tid >> 3;                     // K: 1 row, 16 elems/thr
    const int vd_ = tid >> 2;                     // V: 1 row, 16 elems/thr
    bf16x8 kReg[2], vReg[2];
    auto issue = [&](int kt) {
        int kv0 = kt * 64;
        const unsigned short* ks = &kw[((size_t)(b * 4096 + kv0 + kr_)) * 128 + (tid & 7) * 16];
        kReg[0] = *(const bf16x8*)ks;
        kReg[1] = *(const bf16x8*)(ks + 8);
        const unsigned short* vs = &vTw[((size_t)(b * 128 + vd_)) * 4096 + kv0 + (tid & 3) * 16];
        vReg[0] = *(const bf16x8*)vs;
        vReg[1] = *(const bf16x8*)(vs + 8);
    };

    char* Plw = (char*)&Pl[w][0];

    issue(kt0);
    for (int kt = kt0; kt < kt1; ++kt) {
        __syncthreads();                          // prev-tile readers done
        for (int it = 0; it < 2; ++it)
            *(bf16x8*)((char*)Kl + kr_ * 256 +
                    (((tid & 7) * 32 + it * 16) ^ ((kr_ & 7) << 4))) = kReg[it];
        for (int it = 0; it < 2; ++it)
            *(bf16x8*)((char*)Vl + vd_ * 128 +
                    (((tid & 3) * 32 + it * 16) ^ ((vd_ & 7) << 4))) = vReg[it];
        __syncthreads();                          // tile visible
        if (kt + 1 < kt1) issue(kt + 1);          // hide under compute

        const int kv0 = kt * 64;
        if (kv0 > qrow0 + 15) continue;           // fully masked for this wave

        // S^T = K Q^T : A=K-frag (m=kv), B=Q-frag (n=q). Lane holds
        // s[ni][i] = S[q=qrow0+l15][kv=kv0+ni*16+lh*4+i]  (kv lane-local!)
        f32x4 s[4];
        __builtin_amdgcn_s_setprio(1);
        for (int ni = 0; ni < 4; ++ni) {
            s[ni] = (f32x4){0.f, 0.f, 0.f, 0.f};
            int kr = ni * 16 + l15;
            int sw = (kr & 7) << 4;
            for (int cc = 0; cc < 4; ++cc) {
                bf16x8 bk = *(bf16x8*)((char*)Kl + kr * 256 + ((lh * 16 + cc * 64) ^ sw));
                s[ni] = __builtin_amdgcn_mfma_f32_16x16x32_bf16(bk, qa[cc], s[ni], 0, 0, 0);
            }
        }
        __builtin_amdgcn_s_setprio(0);

        if (kv0 + 63 > qrow0) {                   // causal mask (near-diag only)
            int qg = qrow0 + l15;
            for (int ni = 0; ni < 4; ++ni)
                for (int i = 0; i < 4; ++i)
                    if (kv0 + ni * 16 + lh * 4 + i > qg) s[ni][i] = -INFINITY;
        }
        // P = exp2(s) -> pack 4 consecutive kv as b64, row q=l15, swizzled
        for (int ni = 0; ni < 4; ++ni) {
            float p0 = exp2f(s[ni][0]), p1 = exp2f(s[ni][1]);
            float p2 = exp2f(s[ni][2]), p3 = exp2f(s[ni][3]);
            uint2 pk;
            pk.x = cvt_pk_bf16(p0, p1);
            pk.y = cvt_pk_bf16(p2, p3);
            *(uint2*)(Plw + l15 * 128 + ((ni * 32 + lh * 8) ^ ((l15 & 7) << 4))) = pk;
        }
        bf16x8 pa[2];
        for (int kc = 0; kc < 2; ++kc)
            pa[kc] = *(bf16x8*)(Plw + l15 * 128 +
                    ((kc * 64 + lh * 16) ^ ((l15 & 7) << 4)));
        __builtin_amdgcn_s_setprio(1);
        // row-sums via MFMA against ones
        lsa = __builtin_amdgcn_mfma_f32_16x16x32_bf16(pa[1], ones,
              __builtin_amdgcn_mfma_f32_16x16x32_bf16(pa[0], ones, lsa, 0, 0, 0), 0, 0, 0);
        for (int nd = 0; nd < 8; ++nd) {
            int dr = nd * 16 + l15;
            int sw = (dr & 7) << 4;
            for (int kc = 0; kc < 2; ++kc) {
                bf16x8 bv = *(bf16x8*)((char*)Vl + dr * 128 + ((lh * 16 + kc * 64) ^ sw));
                o[nd] = __builtin_amdgcn_mfma_f32_16x16x32_bf16(pa[kc], bv, o[nd], 0, 0, 0);
            }
        }
        __builtin_amdgcn_s_setprio(0);
    }

    // epilogue: unnormalized partial O (bf16) + l (f32), compact slot
    const int slot_ = b * nCPB + cid;
    unsigned short* po = pO + (size_t)slot_ * 16384;
    for (int nd = 0; nd < 8; ++nd)
        for (int i = 0; i < 4; ++i)
            po[(w * 16 + lh * 4 + i) * 128 + nd * 16 + l15] = f2bf(o[nd][i]);
    if (l15 == 0) {
        float* pl = pL + (size_t)slot_ * 128;
        for (int i = 0; i < 4; ++i)
            pl[w * 16 + lh * 4 + i] = lsa[i];
    }
}

// ---------------- Kernel 4: combine partials (plain sums, no weights) ------
__global__ __launch_bounds__(256) void combine_kernel(
        const unsigned short* __restrict__ pO, const float* __restrict__ pL,
        float* __restrict__ out, int nCPB, int G) {
    int idx = blockIdx.x * 256 + threadIdx.x;     // B*T*16 = 262144 threads
    int row = idx >> 4, d8 = (idx & 15) * 8;
    int b = row >> 12, t = row & 4095;
    int g = t >> 7, rowin = t & 127;
    int a = g / G;
    int nch = a + 1;
    int base = b * nCPB + (G >> 1) * a * (a + 1) + (g - G * a) * (a + 1);

    float den = 0.f;
    float num[8] = {0.f, 0.f, 0.f, 0.f, 0.f, 0.f, 0.f, 0.f};
    for (int cc = 0; cc < nch; ++cc) {
        den += pL[(size_t)(base + cc) * 128 + rowin];
        bf16x8 ov = *(const bf16x8*)&pO[(size_t)(base + cc) * 16384 + rowin * 128 + d8];
        for (int u = 0; u < 8; ++u)
            num[u] += bf2f((unsigned short)ov[u]);
    }
    float inv = 1.f / den;
    for (int u = 0; u < 8; ++u)
        out[(size_t)row * 128 + d8 + u] = num[u] * inv;
}

// ---------------------------------------------------------------------------
extern "C" void kernel_launch(void* const* d_in, const int* in_sizes, int n_in,
                              void* d_out, int out_size, void* d_ws, size_t ws_size,
                              hipStream_t stream) {
    const float* x  = (const float*)d_in[0];
    const float* Wk = (const float*)d_in[1];
    const float* Wq = (const float*)d_in[2];
    const float* Wv = (const float*)d_in[3];
    float* out = (float*)d_out;

    // ws: WbT 786432 | k/q/vT 3*4194304 | pO nslots*32768 | pL nslots*512
    char* ws = (char*)d_ws;
    unsigned short* WbT = (unsigned short*)(ws);
    unsigned short* kw  = (unsigned short*)(ws + 786432);
    unsigned short* qw  = (unsigned short*)(ws + 786432 + 4194304);
    unsigned short* vTw = (unsigned short*)(ws + 786432 + 2 * 4194304);
    size_t base = 786432 + 3 * (size_t)4194304;   // 13369344

    // chunk=4 kv-tiles (272 chunks/batch) if ws allows, else chunk=8 (144)
    int nCPB, G, TPC;
    size_t need4 = base + (size_t)1088 * 32768 + (size_t)1088 * 512;
    if (ws_size >= need4) { nCPB = 272; G = 2; TPC = 4; }
    else                  { nCPB = 144; G = 4; TPC = 8; }
    int nslots = 4 * nCPB;
    unsigned short* pO = (unsigned short*)(ws + base);
    float*          pL = (float*)(ws + base + (size_t)nslots * 32768);

    wconv_kernel<<<1536, 256, 0, stream>>>(Wk, Wq, Wv, WbT);
    qkv_gemm_kernel<<<256, 512, 0, stream>>>(x, WbT, kw, qw, vTw);
    attn_kernel<<<nslots, 512, 0, stream>>>(kw, qw, vTw, pO, pL, nCPB, G, TPC);
    combine_kernel<<<1024, 256, 0, stream>>>(pO, pL, out, nCPB, G);
}